// Round 6
// baseline (83.485 us; speedup 1.0000x reference)
//
#include <hip/hip_runtime.h>
#include <hip/hip_bf16.h>
#include <math.h>

// Problem constants (from reference)
#define INPUT_DIM 30000
#define UNITS     2048
#define NNZ       500000
#define BATCH     32

// ---------------------------------------------------------------------------
// Kernel 1: transpose x [32][30000] -> xt [30000][32] (LDS-tiled, coalesced
// both sides) + zero the ws2/spill accumulator arrays (131072 floats).
// ---------------------------------------------------------------------------
__global__ __launch_bounds__(256) void transpose_k(const float* __restrict__ x,
                                                   float* __restrict__ xt,
                                                   float4* __restrict__ zero4) {
    {
        int g = blockIdx.x * 256 + threadIdx.x;
        if (g < 32768) zero4[g] = make_float4(0.f, 0.f, 0.f, 0.f);
    }
    __shared__ float tile[32][65];                // +1 pad: conflict-free
    const int i0 = blockIdx.x * 64;
    const int t  = threadIdx.x;
    const int w  = t >> 6;                        // wave 0..3
    const int l  = t & 63;                        // lane
    const bool iok = (i0 + l) < INPUT_DIM;
    #pragma unroll
    for (int bb = 0; bb < 8; ++bb) {              // 8 batch rows per wave
        int b = w * 8 + bb;
        tile[b][l] = iok ? x[b * INPUT_DIM + i0 + l] : 0.f;
    }
    __syncthreads();
    float4* __restrict__ xt4 = (float4*)xt;
    #pragma unroll
    for (int rep = 0; rep < 2; ++rep) {
        int f  = t + rep * 256;                   // 0..511 float4 slots
        int il = f >> 3;                          // local i 0..63
        int b4 = f & 7;                           // batch quad 0..7
        if (i0 + il < INPUT_DIM)
            xt4[(size_t)(i0 + il) * 8 + b4] =
                make_float4(tile[b4 * 4 + 0][il], tile[b4 * 4 + 1][il],
                            tile[b4 * 4 + 2][il], tile[b4 * 4 + 3][il]);
    }
}

// ---------------------------------------------------------------------------
// Kernel 2: residue-sliced scatter, register accumulation, ZERO atomics in
// the hot path. Straight-line, branch-free load phase: ALL loads are
// unconditional with clamped indices (R4 post-mortem: conditional loads get
// serialized by the compiler -> VGPR 28, one latency trip per load; clamped
// unconditional loads let it issue 32 vmem ops back-to-back -> ~1 trip total).
// Thread = (rl 0..3, bg 0..3, es 0..31); block owns 4 residues/columns.
// Entries n = r + 2048*(es + 32*k), k=0..7 cover the whole residue class.
// OOB slots: clamp addr to NNZ-1, select val=0 / col=col0 -> zero adds.
// Spill path (col != col0) is the arbitrary-index correctness fallback;
// never taken for this dataset's bijective-stride COO.
// ---------------------------------------------------------------------------
__global__ __launch_bounds__(512, 4) void scatter_k(const int* __restrict__ idx,
                                                    const float* __restrict__ kv,
                                                    const float* __restrict__ xt,
                                                    float* __restrict__ ws2,
                                                    float* __restrict__ spill) {
    __shared__ float part[32 * 128];              // [es][b 0..31][rl 0..3]
    __shared__ int   colA[4];

    const int t    = threadIdx.x;
    const int rl   = t & 3;
    const int bg   = (t >> 2) & 3;
    const int es   = t >> 4;                      // 0..31
    const int r    = blockIdx.x * 4 + rl;         // residue 0..2047
    const int boff = bg * 8;

    // int64 vs int32 index detection (uniform): int64 LE -> high words zero.
    const bool is64 = ((idx[3] | idx[5] | idx[7]) == 0);
    const int  col0 = is64 ? idx[4 * r + 2] : idx[2 * r + 1];

    const int nbase = r + UNITS * es;             // <= 65535

    int   ec[8], rows[8], cols[8];
    float vals[8];
    bool  eok[8];
    #pragma unroll
    for (int k = 0; k < 8; ++k) {
        int e  = nbase + k * (UNITS * 32);        // stride 65536
        eok[k] = e < NNZ;
        ec[k]  = eok[k] ? e : (NNZ - 1);          // clamped: load always legal
    }

    // phase 1: 16 unconditional idx/kv loads
    if (is64) {
        const int4* __restrict__ p = (const int4*)idx;
        #pragma unroll
        for (int k = 0; k < 8; ++k) {
            int4 q  = p[ec[k]];
            rows[k] = q.x;
            cols[k] = eok[k] ? q.z : col0;
            vals[k] = eok[k] ? kv[ec[k]] : 0.f;
        }
    } else {
        const int2* __restrict__ p = (const int2*)idx;
        #pragma unroll
        for (int k = 0; k < 8; ++k) {
            int2 q  = p[ec[k]];
            rows[k] = q.x;
            cols[k] = eok[k] ? q.y : col0;
            vals[k] = eok[k] ? kv[ec[k]] : 0.f;
        }
    }

    // phase 2: 16 unconditional xt gathers (4 bg threads jointly cover the
    // 128B row of each entry; this thread takes its 32B slice)
    float4 g0[8], g1[8];
    #pragma unroll
    for (int k = 0; k < 8; ++k) {
        const float4* __restrict__ xr = (const float4*)(xt + rows[k] * 32 + boff);
        g0[k] = xr[0];
        g1[k] = xr[1];
    }

    // phase 3: register accumulation (spill branch never taken for this data)
    float acc[8];
    #pragma unroll
    for (int j = 0; j < 8; ++j) acc[j] = 0.f;
    #pragma unroll
    for (int k = 0; k < 8; ++k) {
        const float v = vals[k];
        if (cols[k] == col0) {
            acc[0] += v * g0[k].x; acc[1] += v * g0[k].y;
            acc[2] += v * g0[k].z; acc[3] += v * g0[k].w;
            acc[4] += v * g1[k].x; acc[5] += v * g1[k].y;
            acc[6] += v * g1[k].z; acc[7] += v * g1[k].w;
        } else {
            float* __restrict__ sp = spill + cols[k];
            atomicAdd(sp + (boff + 0) * UNITS, v * g0[k].x);
            atomicAdd(sp + (boff + 1) * UNITS, v * g0[k].y);
            atomicAdd(sp + (boff + 2) * UNITS, v * g0[k].z);
            atomicAdd(sp + (boff + 3) * UNITS, v * g0[k].w);
            atomicAdd(sp + (boff + 4) * UNITS, v * g1[k].x);
            atomicAdd(sp + (boff + 5) * UNITS, v * g1[k].y);
            atomicAdd(sp + (boff + 6) * UNITS, v * g1[k].z);
            atomicAdd(sp + (boff + 7) * UNITS, v * g1[k].w);
        }
    }

    // combine 32 es-stripes via plain LDS writes
    #pragma unroll
    for (int bb = 0; bb < 8; ++bb)
        part[es * 128 + (boff + bb) * 4 + rl] = acc[bb];
    if (t < 4) colA[t] = col0;
    __syncthreads();

    if (t < 128) {
        const int rr = t & 3;
        const int b  = t >> 2;                    // 0..31
        float s = 0.f;
        #pragma unroll
        for (int e = 0; e < 32; ++e) s += part[e * 128 + b * 4 + rr];
        // atomic (not plain store): two residues may share col0 under
        // adversarial indices; bijective data -> distinct addrs, no contention
        atomicAdd(&ws2[b * UNITS + colA[rr]], s);
    }
}

// ---------------------------------------------------------------------------
// Kernel 3: out = tanh(ws2 + spill + bias), float4-vectorized. 16384 threads.
// ---------------------------------------------------------------------------
__global__ __launch_bounds__(256) void final_k(const float4* __restrict__ ws2,
                                               const float4* __restrict__ spill,
                                               const float4* __restrict__ bias,
                                               float4* __restrict__ out) {
    int v = blockIdx.x * 256 + threadIdx.x;       // 0..16383
    float4 a  = ws2[v];
    float4 s  = spill[v];
    float4 bb = bias[v & (UNITS / 4 - 1)];
    out[v] = make_float4(tanhf(a.x + s.x + bb.x), tanhf(a.y + s.y + bb.y),
                         tanhf(a.z + s.z + bb.z), tanhf(a.w + s.w + bb.w));
}

// ---------------------------------------------------------------------------
extern "C" void kernel_launch(void* const* d_in, const int* in_sizes, int n_in,
                              void* d_out, int out_size, void* d_ws, size_t ws_size,
                              hipStream_t stream) {
    const float* x    = (const float*)d_in[0];
    const float* kv   = (const float*)d_in[1];
    const float* bias = (const float*)d_in[2];
    const int*   idx  = (const int*)d_in[3];
    float*       out  = (float*)d_out;

    // workspace layout: xt [960000 f] | ws2 [65536 f] | spill [65536 f]
    float* xt    = (float*)d_ws;
    float* ws2   = xt + (size_t)INPUT_DIM * BATCH;
    float* spill = ws2 + BATCH * UNITS;

    transpose_k<<<(INPUT_DIM + 63) / 64, 256, 0, stream>>>(x, xt, (float4*)ws2);
    scatter_k<<<UNITS / 4, 512, 0, stream>>>(idx, kv, xt, ws2, spill);
    final_k<<<BATCH * UNITS / 4 / 256, 256, 0, stream>>>(
        (const float4*)ws2, (const float4*)spill, (const float4*)bias, (float4*)out);
}